// Round 8
// baseline (286.073 us; speedup 1.0000x reference)
//
#include <hip/hip_runtime.h>
#include <hip/hip_bf16.h>
#include <math.h>

#define B_ 4
#define T_ 2048
#define D_ 1024
#define H_ 16
#define HD_ 64

typedef _Float16 f16x8 __attribute__((ext_vector_type(8)));
typedef _Float16 f16x4 __attribute__((ext_vector_type(4)));
typedef float f32x4 __attribute__((ext_vector_type(4)));

// async global->LDS, 16 B per lane, dest = wave-uniform base + lane*16
__device__ __forceinline__ void gload_lds16(const _Float16* g, _Float16* l) {
    __builtin_amdgcn_global_load_lds(
        (const __attribute__((address_space(1))) void*)g,
        (__attribute__((address_space(3))) void*)l,
        16, 0, 0);
}

// ---------------------------------------------------------------------------
// fp32 -> fp16 cast, 4 elems/thread
// ---------------------------------------------------------------------------
__global__ __launch_bounds__(256) void castf(const float* __restrict__ in,
                                             _Float16* __restrict__ out, int n4) {
    const int i = blockIdx.x * 256 + threadIdx.x;
    if (i < n4) {
        const float4 v = ((const float4*)in)[i];
        f16x4 h = {(_Float16)v.x, (_Float16)v.y, (_Float16)v.z, (_Float16)v.w};
        ((f16x4*)out)[i] = h;
    }
}

// fused 4-weight cast: grid.z selects which weight
__global__ __launch_bounds__(256) void castw(const float* __restrict__ a,
                                             const float* __restrict__ b,
                                             const float* __restrict__ c,
                                             const float* __restrict__ d,
                                             _Float16* __restrict__ oa,
                                             _Float16* __restrict__ ob,
                                             _Float16* __restrict__ oc,
                                             _Float16* __restrict__ od) {
    const int z = blockIdx.z;
    const float* in = (z == 0) ? a : (z == 1 ? b : (z == 2 ? c : d));
    _Float16* out = (z == 0) ? oa : (z == 1 ? ob : (z == 2 ? oc : od));
    const int i = blockIdx.x * 256 + threadIdx.x;
    const float4 v = ((const float4*)in)[i];
    f16x4 h = {(_Float16)v.x, (_Float16)v.y, (_Float16)v.z, (_Float16)v.w};
    ((f16x4*)out)[i] = h;
}

// ---------------------------------------------------------------------------
// Fused QKV GEMM + rmsnorm/rotary epilogue.
// Grid (rows=64, cols=8, z=3): id%8 = row-tile%8 -> A-stripe XCD affinity
// (r7: FETCH 135->49 MB). K-loop DOUBLE-BUFFERED with post-barrier
// prefetch: the vmcnt(0) drain at each barrier waits on a stage issued a
// full compute-iteration earlier -> staging latency hidden; 1 barrier/iter.
// LDS 32 KB keeps 5 blocks/CU (VGPR-limited anyway).
// z=0: rms+rotary+0.125*log2e -> qh ; z=1: rms+rotary -> kh ;
// z=2: plain -> vt transposed [b][h][d][T]
// ---------------------------------------------------------------------------
__global__ __launch_bounds__(256) void gemm_qkv(const _Float16* __restrict__ A,
                                                const _Float16* __restrict__ Wq,
                                                const _Float16* __restrict__ Wk,
                                                const _Float16* __restrict__ Wv,
                                                _Float16* __restrict__ qh,
                                                _Float16* __restrict__ kh,
                                                _Float16* __restrict__ vt) {
    constexpr int K = D_;
    const int z = blockIdx.z;
    const _Float16* W = (z == 0) ? Wq : (z == 1 ? Wk : Wv);
    __shared__ _Float16 As[2][128 * 32];
    __shared__ _Float16 Bs[2][128 * 32];
    const int tid = threadIdx.x;
    const int lane = tid & 63, w = tid >> 6;
    const int col = lane & 15, quad = lane >> 4;
    const int wm = w >> 1, wn = w & 1;
    const int row0 = blockIdx.x * 128, col0 = blockIdx.y * 128;
    const int sr = lane >> 2, sc = (lane & 3) * 8;
    // per-thread staging source base (row it loads within the 128-stripe)
    const _Float16* abase = A + (size_t)(row0 + sr) * K + sc;
    const _Float16* wbase = W + (size_t)(col0 + sr) * K + sc;

    f32x4 acc[4][4];
#pragma unroll
    for (int i = 0; i < 4; ++i)
#pragma unroll
        for (int j = 0; j < 4; ++j) acc[i][j] = (f32x4){0.f, 0.f, 0.f, 0.f};

    // prestage kt=0 -> buffer 0
#pragma unroll
    for (int it = 0; it < 2; ++it) {
        const int rb = it * 64 + w * 16;
        gload_lds16(abase + (size_t)rb * K, As[0] + rb * 32);
        gload_lds16(wbase + (size_t)rb * K, Bs[0] + rb * 32);
    }

    for (int kt = 0; kt < K / 32; ++kt) {
        const int cur = kt & 1;
        __syncthreads();  // drains stage(kt), issued one compute-iter ago
        if (kt + 1 < K / 32) {
            const int k1 = (kt + 1) * 32;
#pragma unroll
            for (int it = 0; it < 2; ++it) {
                const int rb = it * 64 + w * 16;
                gload_lds16(abase + (size_t)rb * K + k1, As[cur ^ 1] + rb * 32);
                gload_lds16(wbase + (size_t)rb * K + k1, Bs[cur ^ 1] + rb * 32);
            }
        }
        f16x8 af[4], bf[4];
#pragma unroll
        for (int i = 0; i < 4; ++i) {
            af[i] = *(const f16x8*)&As[cur][(wm * 64 + i * 16 + col) * 32 + quad * 8];
            bf[i] = *(const f16x8*)&Bs[cur][(wn * 64 + i * 16 + col) * 32 + quad * 8];
        }
#pragma unroll
        for (int mi = 0; mi < 4; ++mi)
#pragma unroll
            for (int ni = 0; ni < 4; ++ni)
                acc[mi][ni] = __builtin_amdgcn_mfma_f32_16x16x32_f16(af[mi], bf[ni],
                                                                     acc[mi][ni], 0, 0, 0);
        // no trailing barrier: next iteration's barrier protects the buffers
    }

    if (z < 2) {
        _Float16* C = (z == 0) ? qh : kh;
        const float qscale = (z == 0) ? 0.18033688011112042f : 1.0f;  // 0.125*log2(e)
        const float fr = exp2f(-10.0f * (float)col * (1.0f / 15.0f));
#pragma unroll
        for (int mi = 0; mi < 4; ++mi) {
            float ssq[4];
#pragma unroll
            for (int r = 0; r < 4; ++r) {
                float t = 0.f;
#pragma unroll
                for (int ni = 0; ni < 4; ++ni) t += acc[mi][ni][r] * acc[mi][ni][r];
                ssq[r] = t;
            }
#pragma unroll
            for (int st = 1; st < 16; st <<= 1)
#pragma unroll
                for (int r = 0; r < 4; ++r) ssq[r] += __shfl_xor(ssq[r], st, 64);
            const int rowb = row0 + wm * 64 + mi * 16 + quad * 4;
#pragma unroll
            for (int r = 0; r < 4; ++r) {
                const float scl = rsqrtf(ssq[r] * (1.0f / 64.0f) + 1e-6f) * qscale;
                const int t = (rowb + r) & (T_ - 1);
                float s, c;
                __sincosf((float)t * fr, &s, &c);
                const float x0 = acc[mi][0][r] * scl;
                const float x1 = acc[mi][1][r] * scl;
                const float x2 = acc[mi][2][r] * scl;
                const float x3 = acc[mi][3][r] * scl;
                const float y0 = fmaf(x0, c, x2 * s);
                const float y2 = fmaf(x2, c, -x0 * s);
                const size_t base = (size_t)(rowb + r) * D_ + col0 + wn * 64 + col;
                C[base + 0]  = (_Float16)y0;
                C[base + 16] = (_Float16)x1;
                C[base + 32] = (_Float16)y2;
                C[base + 48] = (_Float16)x3;
            }
        }
    } else {
        const int hh = blockIdx.y * 2 + wn;
#pragma unroll
        for (int mi = 0; mi < 4; ++mi) {
            const int row = row0 + wm * 64 + mi * 16 + quad * 4;
            const int bb = row >> 11;
            const int t0m = row & (T_ - 1);
#pragma unroll
            for (int ni = 0; ni < 4; ++ni) {
                const int d = ni * 16 + col;
                f16x4 pk = {(_Float16)acc[mi][ni][0], (_Float16)acc[mi][ni][1],
                            (_Float16)acc[mi][ni][2], (_Float16)acc[mi][ni][3]};
                *(f16x4*)&vt[((size_t)(bb * H_ + hh) * HD_ + d) * T_ + t0m] = pk;
            }
        }
    }
}

// ---------------------------------------------------------------------------
// WO GEMM: out[M,N] = A[M,K] @ W[N,K]^T, fp16 in, fp32 out.
// Same double-buffered K-loop; grid (rows=64, cols=8) A-affinity.
// ---------------------------------------------------------------------------
__global__ __launch_bounds__(256) void gemm_wo(const _Float16* __restrict__ A,
                                               const _Float16* __restrict__ W,
                                               float* __restrict__ C) {
    constexpr int K = D_, N = D_;
    __shared__ _Float16 As[2][128 * 32];
    __shared__ _Float16 Bs[2][128 * 32];
    const int tid = threadIdx.x;
    const int lane = tid & 63, w = tid >> 6;
    const int col = lane & 15, quad = lane >> 4;
    const int wm = w >> 1, wn = w & 1;
    const int row0 = blockIdx.x * 128, col0 = blockIdx.y * 128;
    const int sr = lane >> 2, sc = (lane & 3) * 8;
    const _Float16* abase = A + (size_t)(row0 + sr) * K + sc;
    const _Float16* wbase = W + (size_t)(col0 + sr) * K + sc;

    f32x4 acc[4][4];
#pragma unroll
    for (int i = 0; i < 4; ++i)
#pragma unroll
        for (int j = 0; j < 4; ++j) acc[i][j] = (f32x4){0.f, 0.f, 0.f, 0.f};

#pragma unroll
    for (int it = 0; it < 2; ++it) {
        const int rb = it * 64 + w * 16;
        gload_lds16(abase + (size_t)rb * K, As[0] + rb * 32);
        gload_lds16(wbase + (size_t)rb * K, Bs[0] + rb * 32);
    }

    for (int kt = 0; kt < K / 32; ++kt) {
        const int cur = kt & 1;
        __syncthreads();
        if (kt + 1 < K / 32) {
            const int k1 = (kt + 1) * 32;
#pragma unroll
            for (int it = 0; it < 2; ++it) {
                const int rb = it * 64 + w * 16;
                gload_lds16(abase + (size_t)rb * K + k1, As[cur ^ 1] + rb * 32);
                gload_lds16(wbase + (size_t)rb * K + k1, Bs[cur ^ 1] + rb * 32);
            }
        }
        f16x8 af[4], bf[4];
#pragma unroll
        for (int i = 0; i < 4; ++i) {
            af[i] = *(const f16x8*)&As[cur][(wm * 64 + i * 16 + col) * 32 + quad * 8];
            bf[i] = *(const f16x8*)&Bs[cur][(wn * 64 + i * 16 + col) * 32 + quad * 8];
        }
#pragma unroll
        for (int mi = 0; mi < 4; ++mi)
#pragma unroll
            for (int ni = 0; ni < 4; ++ni)
                acc[mi][ni] = __builtin_amdgcn_mfma_f32_16x16x32_f16(af[mi], bf[ni],
                                                                     acc[mi][ni], 0, 0, 0);
    }
#pragma unroll
    for (int mi = 0; mi < 4; ++mi)
#pragma unroll
        for (int ni = 0; ni < 4; ++ni)
#pragma unroll
            for (int r = 0; r < 4; ++r)
                C[(size_t)(row0 + wm * 64 + mi * 16 + quad * 4 + r) * N +
                  col0 + wn * 64 + ni * 16 + col] = acc[mi][ni][r];
}

// ---------------------------------------------------------------------------
// MFMA flash attention (fp16 in/out) — round-6 single-buffer version
// (4 blocks/CU; the r7 dbuf cost occupancy 4->2 and regressed ~14 us).
// 512 thr = 8 waves, 128 q/block; XCD-aware grid (64 bh, 8 pair);
// diagonal pairing {y, 15-y} -> uniform 34 K-tiles; S^T form (A=K, B=Q);
// global_load_lds staging with XOR-chunk swizzle; bounded-score softmax.
// ---------------------------------------------------------------------------
#define LDP 88

__global__ __launch_bounds__(512) void flash_mfma(const _Float16* __restrict__ qh,
                                                  const _Float16* __restrict__ kh,
                                                  const _Float16* __restrict__ vt,
                                                  _Float16* __restrict__ o) {
    __shared__ _Float16 Kl[64 * 64];
    __shared__ _Float16 Vl[64 * 64];
    __shared__ _Float16 Pl[8][16 * LDP];
    const int tid = threadIdx.x;
    const int lane = tid & 63, w = tid >> 6;           // w in [0,8)
    const int col = lane & 15, quad = lane >> 4;
    const int bh = blockIdx.x, b = bh >> 4, h = bh & 15;
    const int srow = lane >> 3;                        // row-in-8 for staging
    const int schunk = (lane & 7) ^ srow;              // global-side swizzle
    const int sw = col & 7;                            // read-side swizzle key

    for (int phase = 0; phase < 2; ++phase) {
        const int qt = (phase == 0) ? (int)blockIdx.y : (15 - (int)blockIdx.y);
        const int q0 = qt * 128;

        // Q as B-operand: lane holds Q[q=q0+16w+col][d = quad*8+j (+32)]
        const int tq = q0 + w * 16 + col;
        const _Float16* qp = qh + ((size_t)(b * T_ + tq) * H_ + h) * HD_ + quad * 8;
        const f16x8 qB0 = *(const f16x8*)(qp);
        const f16x8 qB1 = *(const f16x8*)(qp + 32);

        f32x4 oa[4];
#pragma unroll
        for (int i = 0; i < 4; ++i) oa[i] = (f32x4){0.f, 0.f, 0.f, 0.f};
        float l_ = 0.f;  // per-lane partial denom for q = col

        const int nkt = 2 * qt + 2;
        for (int kt = 0; kt < nkt; ++kt) {
            const int k0 = kt * 64;
            // ---- stage K[key][d], Vt[d][key]: 512 thr x 16 B = full tile ----
            {
                const int r = w * 8 + srow;
                gload_lds16(kh + ((size_t)(b * T_ + k0 + r) * H_ + h) * HD_ + schunk * 8,
                            Kl + (w * 8) * 64);
                gload_lds16(vt + ((size_t)(b * H_ + h) * HD_ + r) * T_ + k0 + schunk * 8,
                            Vl + (w * 8) * 64);
            }
            __syncthreads();

            // ---- S^T[key][q]: A = K rows, B = Q (in regs) ----
            f32x4 s[4];
#pragma unroll
            for (int tn = 0; tn < 4; ++tn) {
                const _Float16* kp = &Kl[(tn * 16 + col) * 64];
                const f16x8 kA0 = *(const f16x8*)(kp + ((quad ^ sw) << 3));
                const f16x8 kA1 = *(const f16x8*)(kp + (((quad | 4) ^ sw) << 3));
                f32x4 a = (f32x4){0.f, 0.f, 0.f, 0.f};
                a = __builtin_amdgcn_mfma_f32_16x16x32_f16(kA0, qB0, a, 0, 0, 0);
                a = __builtin_amdgcn_mfma_f32_16x16x32_f16(kA1, qB1, a, 0, 0, 0);
                s[tn] = a;
            }

            // ---- causal mask: any key in tile beyond this wave's q rows ----
            if (k0 + 63 > q0 + w * 16) {
                const int qq = q0 + w * 16 + col;
#pragma unroll
                for (int tn = 0; tn < 4; ++tn)
#pragma unroll
                    for (int r = 0; r < 4; ++r) {
                        const int key = k0 + tn * 16 + quad * 4 + r;
                        if (key > qq) s[tn][r] = -1e30f;
                    }
            }

            // ---- p = exp2(s); l accumulate; packed P store (4x b64) ----
#pragma unroll
            for (int tn = 0; tn < 4; ++tn) {
                f16x4 pk;
#pragma unroll
                for (int r = 0; r < 4; ++r) {
                    const float p = exp2f(s[tn][r]);
                    l_ += p;
                    pk[r] = (_Float16)p;
                }
                *(f16x4*)&Pl[w][col * LDP + tn * 16 + quad * 4] = pk;
            }

            // ---- O[q][d] += P @ V (Pl[w] wave-private, no barrier) ----
            const f16x8 pA0 = *(const f16x8*)&Pl[w][col * LDP + quad * 8];
            const f16x8 pA1 = *(const f16x8*)&Pl[w][col * LDP + quad * 8 + 32];
#pragma unroll
            for (int tn = 0; tn < 4; ++tn) {
                const _Float16* vp = &Vl[(tn * 16 + col) * 64];
                const f16x8 vB0 = *(const f16x8*)(vp + ((quad ^ sw) << 3));
                const f16x8 vB1 = *(const f16x8*)(vp + (((quad | 4) ^ sw) << 3));
                oa[tn] = __builtin_amdgcn_mfma_f32_16x16x32_f16(pA0, vB0, oa[tn], 0, 0, 0);
                oa[tn] = __builtin_amdgcn_mfma_f32_16x16x32_f16(pA1, vB1, oa[tn], 0, 0, 0);
            }
            __syncthreads();
        }

        // ---- finish l (sum quads), redistribute to O rows, write ----
        l_ += __shfl_xor(l_, 16, 64);
        l_ += __shfl_xor(l_, 32, 64);
        const float linv = 1.0f / l_;
        float inv[4];
#pragma unroll
        for (int r = 0; r < 4; ++r) inv[r] = __shfl(linv, quad * 4 + r, 64);
#pragma unroll
        for (int tn = 0; tn < 4; ++tn)
#pragma unroll
            for (int r = 0; r < 4; ++r)
                o[((size_t)(b * T_ + q0 + w * 16 + quad * 4 + r) * H_ + h) * HD_ + tn * 16 + col] =
                    (_Float16)(oa[tn][r] * inv[r]);
    }
}

// ---------------------------------------------------------------------------
extern "C" void kernel_launch(void* const* d_in, const int* in_sizes, int n_in,
                              void* d_out, int out_size, void* d_ws, size_t ws_size,
                              hipStream_t stream) {
    const float* x  = (const float*)d_in[0];
    const float* wq = (const float*)d_in[1];
    const float* wk = (const float*)d_in[2];
    const float* wv = (const float*)d_in[3];
    const float* wo = (const float*)d_in[4];
    float* out = (float*)d_out;

    const size_t NE = (size_t)B_ * T_ * D_;   // 8,388,608
    const size_t WE = (size_t)D_ * D_;        // 1,048,576
    _Float16* xh  = (_Float16*)d_ws;
    _Float16* qh  = xh + NE;
    _Float16* kh  = qh + NE;
    _Float16* vth = kh + NE;
    _Float16* oh  = vth + NE;
    _Float16* wqh = oh + NE;
    _Float16* wkh = wqh + WE;
    _Float16* wvh = wkh + WE;
    _Float16* woh = wvh + WE;

    castf<<<NE / 1024, 256, 0, stream>>>(x, xh, (int)(NE / 4));
    castw<<<dim3(WE / 1024, 1, 4), 256, 0, stream>>>(wq, wk, wv, wo,
                                                     wqh, wkh, wvh, woh);

    gemm_qkv<<<dim3((B_ * T_) / 128, D_ / 128, 3), 256, 0, stream>>>(
        xh, wqh, wkh, wvh, qh, kh, vth);

    flash_mfma<<<dim3(B_ * H_, 8, 1), 512, 0, stream>>>(qh, kh, vth, oh);

    gemm_wo<<<dim3((B_ * T_) / 128, D_ / 128, 1), 256, 0, stream>>>(oh, woh, out);
}

// Round 9
// 279.766 us; speedup vs baseline: 1.0225x; 1.0225x over previous
//
#include <hip/hip_runtime.h>
#include <hip/hip_bf16.h>
#include <math.h>

#define B_ 4
#define T_ 2048
#define D_ 1024
#define H_ 16
#define HD_ 64

typedef _Float16 f16x8 __attribute__((ext_vector_type(8)));
typedef _Float16 f16x4 __attribute__((ext_vector_type(4)));
typedef float f32x4 __attribute__((ext_vector_type(4)));

// async global->LDS, 16 B per lane, dest = wave-uniform base + lane*16
__device__ __forceinline__ void gload_lds16(const _Float16* g, _Float16* l) {
    __builtin_amdgcn_global_load_lds(
        (const __attribute__((address_space(1))) void*)g,
        (__attribute__((address_space(3))) void*)l,
        16, 0, 0);
}

// ---------------------------------------------------------------------------
// fp32 -> fp16 cast, 4 elems/thread
// ---------------------------------------------------------------------------
__global__ __launch_bounds__(256) void castf(const float* __restrict__ in,
                                             _Float16* __restrict__ out, int n4) {
    const int i = blockIdx.x * 256 + threadIdx.x;
    if (i < n4) {
        const float4 v = ((const float4*)in)[i];
        f16x4 h = {(_Float16)v.x, (_Float16)v.y, (_Float16)v.z, (_Float16)v.w};
        ((f16x4*)out)[i] = h;
    }
}

// fused 4-weight cast: grid.z selects which weight
__global__ __launch_bounds__(256) void castw(const float* __restrict__ a,
                                             const float* __restrict__ b,
                                             const float* __restrict__ c,
                                             const float* __restrict__ d,
                                             _Float16* __restrict__ oa,
                                             _Float16* __restrict__ ob,
                                             _Float16* __restrict__ oc,
                                             _Float16* __restrict__ od) {
    const int z = blockIdx.z;
    const float* in = (z == 0) ? a : (z == 1 ? b : (z == 2 ? c : d));
    _Float16* out = (z == 0) ? oa : (z == 1 ? ob : (z == 2 ? oc : od));
    const int i = blockIdx.x * 256 + threadIdx.x;
    const float4 v = ((const float4*)in)[i];
    f16x4 h = {(_Float16)v.x, (_Float16)v.y, (_Float16)v.z, (_Float16)v.w};
    ((f16x4*)out)[i] = h;
}

// ---------------------------------------------------------------------------
// Fused QKV GEMM + rmsnorm/rotary epilogue (r7 single-buffer version —
// measured best; r8 dbuf was neutral-time, +VALU).
// Grid (rows=64, cols=8, z=3): id%8 = row-tile%8 -> A-stripe XCD affinity.
// z=0: rms+rotary+0.125*log2e -> qh ; z=1: rms+rotary -> kh ;
// z=2: plain -> vt transposed [b][h][d][T]
// ---------------------------------------------------------------------------
__global__ __launch_bounds__(256) void gemm_qkv(const _Float16* __restrict__ A,
                                                const _Float16* __restrict__ Wq,
                                                const _Float16* __restrict__ Wk,
                                                const _Float16* __restrict__ Wv,
                                                _Float16* __restrict__ qh,
                                                _Float16* __restrict__ kh,
                                                _Float16* __restrict__ vt) {
    constexpr int K = D_;
    const int z = blockIdx.z;
    const _Float16* W = (z == 0) ? Wq : (z == 1 ? Wk : Wv);
    __shared__ _Float16 As[128 * 32];
    __shared__ _Float16 Bs[128 * 32];
    const int tid = threadIdx.x;
    const int lane = tid & 63, w = tid >> 6;
    const int col = lane & 15, quad = lane >> 4;
    const int wm = w >> 1, wn = w & 1;
    const int row0 = blockIdx.x * 128, col0 = blockIdx.y * 128;
    const int sr = lane >> 2, sc = (lane & 3) * 8;

    f32x4 acc[4][4];
#pragma unroll
    for (int i = 0; i < 4; ++i)
#pragma unroll
        for (int j = 0; j < 4; ++j) acc[i][j] = (f32x4){0.f, 0.f, 0.f, 0.f};

    for (int kt = 0; kt < K / 32; ++kt) {
        const int k0 = kt * 32;
#pragma unroll
        for (int it = 0; it < 2; ++it) {
            const int rb = it * 64 + w * 16;
            gload_lds16(A + (size_t)(row0 + rb + sr) * K + k0 + sc, As + rb * 32);
            gload_lds16(W + (size_t)(col0 + rb + sr) * K + k0 + sc, Bs + rb * 32);
        }
        __syncthreads();
        f16x8 af[4], bf[4];
#pragma unroll
        for (int i = 0; i < 4; ++i) {
            af[i] = *(const f16x8*)&As[(wm * 64 + i * 16 + col) * 32 + quad * 8];
            bf[i] = *(const f16x8*)&Bs[(wn * 64 + i * 16 + col) * 32 + quad * 8];
        }
#pragma unroll
        for (int mi = 0; mi < 4; ++mi)
#pragma unroll
            for (int ni = 0; ni < 4; ++ni)
                acc[mi][ni] = __builtin_amdgcn_mfma_f32_16x16x32_f16(af[mi], bf[ni],
                                                                     acc[mi][ni], 0, 0, 0);
        __syncthreads();
    }

    if (z < 2) {
        _Float16* C = (z == 0) ? qh : kh;
        const float qscale = (z == 0) ? 0.18033688011112042f : 1.0f;  // 0.125*log2(e)
        const float fr = exp2f(-10.0f * (float)col * (1.0f / 15.0f));
#pragma unroll
        for (int mi = 0; mi < 4; ++mi) {
            float ssq[4];
#pragma unroll
            for (int r = 0; r < 4; ++r) {
                float t = 0.f;
#pragma unroll
                for (int ni = 0; ni < 4; ++ni) t += acc[mi][ni][r] * acc[mi][ni][r];
                ssq[r] = t;
            }
#pragma unroll
            for (int st = 1; st < 16; st <<= 1)
#pragma unroll
                for (int r = 0; r < 4; ++r) ssq[r] += __shfl_xor(ssq[r], st, 64);
            const int rowb = row0 + wm * 64 + mi * 16 + quad * 4;
#pragma unroll
            for (int r = 0; r < 4; ++r) {
                const float scl = rsqrtf(ssq[r] * (1.0f / 64.0f) + 1e-6f) * qscale;
                const int t = (rowb + r) & (T_ - 1);
                float s, c;
                __sincosf((float)t * fr, &s, &c);
                const float x0 = acc[mi][0][r] * scl;
                const float x1 = acc[mi][1][r] * scl;
                const float x2 = acc[mi][2][r] * scl;
                const float x3 = acc[mi][3][r] * scl;
                const float y0 = fmaf(x0, c, x2 * s);
                const float y2 = fmaf(x2, c, -x0 * s);
                const size_t base = (size_t)(rowb + r) * D_ + col0 + wn * 64 + col;
                C[base + 0]  = (_Float16)y0;
                C[base + 16] = (_Float16)x1;
                C[base + 32] = (_Float16)y2;
                C[base + 48] = (_Float16)x3;
            }
        }
    } else {
        const int hh = blockIdx.y * 2 + wn;
#pragma unroll
        for (int mi = 0; mi < 4; ++mi) {
            const int row = row0 + wm * 64 + mi * 16 + quad * 4;
            const int bb = row >> 11;
            const int t0m = row & (T_ - 1);
#pragma unroll
            for (int ni = 0; ni < 4; ++ni) {
                const int d = ni * 16 + col;
                f16x4 pk = {(_Float16)acc[mi][ni][0], (_Float16)acc[mi][ni][1],
                            (_Float16)acc[mi][ni][2], (_Float16)acc[mi][ni][3]};
                *(f16x4*)&vt[((size_t)(bb * H_ + hh) * HD_ + d) * T_ + t0m] = pk;
            }
        }
    }
}

// ---------------------------------------------------------------------------
// WO GEMM (r7 single-buffer): out[M,N] = A[M,K] @ W[N,K]^T, fp16 in, fp32 out.
// ---------------------------------------------------------------------------
__global__ __launch_bounds__(256) void gemm_wo(const _Float16* __restrict__ A,
                                               const _Float16* __restrict__ W,
                                               float* __restrict__ C) {
    constexpr int K = D_, N = D_;
    __shared__ _Float16 As[128 * 32];
    __shared__ _Float16 Bs[128 * 32];
    const int tid = threadIdx.x;
    const int lane = tid & 63, w = tid >> 6;
    const int col = lane & 15, quad = lane >> 4;
    const int wm = w >> 1, wn = w & 1;
    const int row0 = blockIdx.x * 128, col0 = blockIdx.y * 128;
    const int sr = lane >> 2, sc = (lane & 3) * 8;

    f32x4 acc[4][4];
#pragma unroll
    for (int i = 0; i < 4; ++i)
#pragma unroll
        for (int j = 0; j < 4; ++j) acc[i][j] = (f32x4){0.f, 0.f, 0.f, 0.f};

    for (int kt = 0; kt < K / 32; ++kt) {
        const int k0 = kt * 32;
#pragma unroll
        for (int it = 0; it < 2; ++it) {
            const int rb = it * 64 + w * 16;
            gload_lds16(A + (size_t)(row0 + rb + sr) * K + k0 + sc, As + rb * 32);
            gload_lds16(W + (size_t)(col0 + rb + sr) * K + k0 + sc, Bs + rb * 32);
        }
        __syncthreads();
        f16x8 af[4], bf[4];
#pragma unroll
        for (int i = 0; i < 4; ++i) {
            af[i] = *(const f16x8*)&As[(wm * 64 + i * 16 + col) * 32 + quad * 8];
            bf[i] = *(const f16x8*)&Bs[(wn * 64 + i * 16 + col) * 32 + quad * 8];
        }
#pragma unroll
        for (int mi = 0; mi < 4; ++mi)
#pragma unroll
            for (int ni = 0; ni < 4; ++ni)
                acc[mi][ni] = __builtin_amdgcn_mfma_f32_16x16x32_f16(af[mi], bf[ni],
                                                                     acc[mi][ni], 0, 0, 0);
        __syncthreads();
    }
#pragma unroll
    for (int mi = 0; mi < 4; ++mi)
#pragma unroll
        for (int ni = 0; ni < 4; ++ni)
#pragma unroll
            for (int r = 0; r < 4; ++r)
                C[(size_t)(row0 + wm * 64 + mi * 16 + quad * 4 + r) * N +
                  col0 + wn * 64 + ni * 16 + col] = acc[mi][ni][r];
}

// ---------------------------------------------------------------------------
// MFMA flash attention v3 (fp16 in/out). 256 thr = 4 waves; wave w owns
// 32 q rows (two 16-row halves). One 128-q tile per block.
// Grid (bh=64, y=16), qt = 15-y (longest blocks dispatched FIRST),
// 1024 blocks = 4/CU -> ALL resident, no tail; id%8 = bh%8 XCD affinity.
// Key change vs r8: each K/V LDS fragment read feeds TWO MFMAs (shared
// across the wave's two q-halves) -> LDS-pipe cyc per work unit ~0.65x.
// S^T form (A=K, B=Q); bounded-score softmax (no max pass, l additive);
// global_load_lds staging with XOR-chunk swizzle.
// ---------------------------------------------------------------------------
#define LDP 88

__global__ __launch_bounds__(256) void flash_mfma(const _Float16* __restrict__ qh,
                                                  const _Float16* __restrict__ kh,
                                                  const _Float16* __restrict__ vt,
                                                  _Float16* __restrict__ o) {
    __shared__ _Float16 Kl[64 * 64];
    __shared__ _Float16 Vl[64 * 64];
    __shared__ _Float16 Pl[4][32 * LDP];
    const int tid = threadIdx.x;
    const int lane = tid & 63, w = tid >> 6;           // w in [0,4)
    const int col = lane & 15, quad = lane >> 4;
    const int bh = blockIdx.x, b = bh >> 4, h = bh & 15;
    const int qt = 15 - (int)blockIdx.y;               // longest first
    const int q0 = qt * 128;
    const int srow = lane >> 3;                        // row-in-8 for staging
    const int schunk = ((lane & 7) ^ srow) * 8;        // global-side swizzle
    const int sw = col & 7;                            // read-side swizzle key

    // Q as B-operand, two q-halves: qa = q0+w*32+col, qb = qa+16
    const int qa = q0 + w * 32 + col;
    const _Float16* qpa = qh + ((size_t)(b * T_ + qa) * H_ + h) * HD_ + quad * 8;
    const f16x8 qB0a = *(const f16x8*)(qpa);
    const f16x8 qB1a = *(const f16x8*)(qpa + 32);
    const _Float16* qpb = qpa + (size_t)16 * D_;
    const f16x8 qB0b = *(const f16x8*)(qpb);
    const f16x8 qB1b = *(const f16x8*)(qpb + 32);

    f32x4 oaa[4], oab[4];
#pragma unroll
    for (int i = 0; i < 4; ++i) {
        oaa[i] = (f32x4){0.f, 0.f, 0.f, 0.f};
        oab[i] = (f32x4){0.f, 0.f, 0.f, 0.f};
    }
    float la = 0.f, lb = 0.f;  // per-lane denom partials (q = qa / qb)

    const int nkt = 2 * qt + 2;
    for (int kt = 0; kt < nkt; ++kt) {
        const int k0 = kt * 64;
        // ---- stage K[key][d], Vt[d][key]: 256 thr x 2 rounds x 16 B ----
#pragma unroll
        for (int half = 0; half < 2; ++half) {
            const int r = half * 32 + w * 8 + srow;
            gload_lds16(kh + ((size_t)(b * T_ + k0 + r) * H_ + h) * HD_ + schunk,
                        Kl + (half * 32 + w * 8) * 64);
            gload_lds16(vt + ((size_t)(b * H_ + h) * HD_ + r) * T_ + k0 + schunk,
                        Vl + (half * 32 + w * 8) * 64);
        }
        __syncthreads();

        // ---- S^T[key][q] for both q-halves; K frags shared ----
        f32x4 sa[4], sb[4];
#pragma unroll
        for (int tn = 0; tn < 4; ++tn) {
            const _Float16* kp = &Kl[(tn * 16 + col) * 64];
            const f16x8 kA0 = *(const f16x8*)(kp + ((quad ^ sw) << 3));
            const f16x8 kA1 = *(const f16x8*)(kp + (((quad | 4) ^ sw) << 3));
            f32x4 xa = (f32x4){0.f, 0.f, 0.f, 0.f};
            f32x4 xb = (f32x4){0.f, 0.f, 0.f, 0.f};
            xa = __builtin_amdgcn_mfma_f32_16x16x32_f16(kA0, qB0a, xa, 0, 0, 0);
            xb = __builtin_amdgcn_mfma_f32_16x16x32_f16(kA0, qB0b, xb, 0, 0, 0);
            xa = __builtin_amdgcn_mfma_f32_16x16x32_f16(kA1, qB1a, xa, 0, 0, 0);
            xb = __builtin_amdgcn_mfma_f32_16x16x32_f16(kA1, qB1b, xb, 0, 0, 0);
            sa[tn] = xa;
            sb[tn] = xb;
        }

        // ---- causal mask ----
        if (k0 + 63 > q0 + w * 32) {
#pragma unroll
            for (int tn = 0; tn < 4; ++tn)
#pragma unroll
                for (int r = 0; r < 4; ++r) {
                    const int key = k0 + tn * 16 + quad * 4 + r;
                    if (key > qa) sa[tn][r] = -1e30f;
                    if (key > qa + 16) sb[tn][r] = -1e30f;
                }
        }

        // ---- p = exp2(s); l accumulate; packed P stores (b64) ----
#pragma unroll
        for (int tn = 0; tn < 4; ++tn) {
            f16x4 pka, pkb;
#pragma unroll
            for (int r = 0; r < 4; ++r) {
                const float pa = exp2f(sa[tn][r]);
                const float pb = exp2f(sb[tn][r]);
                la += pa;
                lb += pb;
                pka[r] = (_Float16)pa;
                pkb[r] = (_Float16)pb;
            }
            *(f16x4*)&Pl[w][col * LDP + tn * 16 + quad * 4] = pka;
            *(f16x4*)&Pl[w][(col + 16) * LDP + tn * 16 + quad * 4] = pkb;
        }

        // ---- O += P @ V for both halves; V frags shared ----
        const f16x8 pA0a = *(const f16x8*)&Pl[w][col * LDP + quad * 8];
        const f16x8 pA1a = *(const f16x8*)&Pl[w][col * LDP + quad * 8 + 32];
        const f16x8 pA0b = *(const f16x8*)&Pl[w][(col + 16) * LDP + quad * 8];
        const f16x8 pA1b = *(const f16x8*)&Pl[w][(col + 16) * LDP + quad * 8 + 32];
#pragma unroll
        for (int tn = 0; tn < 4; ++tn) {
            const _Float16* vp = &Vl[(tn * 16 + col) * 64];
            const f16x8 vB0 = *(const f16x8*)(vp + ((quad ^ sw) << 3));
            const f16x8 vB1 = *(const f16x8*)(vp + (((quad | 4) ^ sw) << 3));
            oaa[tn] = __builtin_amdgcn_mfma_f32_16x16x32_f16(pA0a, vB0, oaa[tn], 0, 0, 0);
            oab[tn] = __builtin_amdgcn_mfma_f32_16x16x32_f16(pA0b, vB0, oab[tn], 0, 0, 0);
            oaa[tn] = __builtin_amdgcn_mfma_f32_16x16x32_f16(pA1a, vB1, oaa[tn], 0, 0, 0);
            oab[tn] = __builtin_amdgcn_mfma_f32_16x16x32_f16(pA1b, vB1, oab[tn], 0, 0, 0);
        }
        __syncthreads();
    }

    // ---- finish l (sum quads), redistribute to O rows, write both halves ----
    la += __shfl_xor(la, 16, 64);
    la += __shfl_xor(la, 32, 64);
    lb += __shfl_xor(lb, 16, 64);
    lb += __shfl_xor(lb, 32, 64);
    const float linva = 1.0f / la;
    const float linvb = 1.0f / lb;
    float inva[4], invb[4];
#pragma unroll
    for (int r = 0; r < 4; ++r) {
        inva[r] = __shfl(linva, quad * 4 + r, 64);
        invb[r] = __shfl(linvb, quad * 4 + r, 64);
    }
    const int qrow = q0 + w * 32 + quad * 4;
#pragma unroll
    for (int tn = 0; tn < 4; ++tn)
#pragma unroll
        for (int r = 0; r < 4; ++r) {
            o[((size_t)(b * T_ + qrow + r) * H_ + h) * HD_ + tn * 16 + col] =
                (_Float16)(oaa[tn][r] * inva[r]);
            o[((size_t)(b * T_ + qrow + 16 + r) * H_ + h) * HD_ + tn * 16 + col] =
                (_Float16)(oab[tn][r] * invb[r]);
        }
}

// ---------------------------------------------------------------------------
extern "C" void kernel_launch(void* const* d_in, const int* in_sizes, int n_in,
                              void* d_out, int out_size, void* d_ws, size_t ws_size,
                              hipStream_t stream) {
    const float* x  = (const float*)d_in[0];
    const float* wq = (const float*)d_in[1];
    const float* wk = (const float*)d_in[2];
    const float* wv = (const float*)d_in[3];
    const float* wo = (const float*)d_in[4];
    float* out = (float*)d_out;

    const size_t NE = (size_t)B_ * T_ * D_;   // 8,388,608
    const size_t WE = (size_t)D_ * D_;        // 1,048,576
    _Float16* xh  = (_Float16*)d_ws;
    _Float16* qh  = xh + NE;
    _Float16* kh  = qh + NE;
    _Float16* vth = kh + NE;
    _Float16* oh  = vth + NE;
    _Float16* wqh = oh + NE;
    _Float16* wkh = wqh + WE;
    _Float16* wvh = wkh + WE;
    _Float16* woh = wvh + WE;

    castf<<<NE / 1024, 256, 0, stream>>>(x, xh, (int)(NE / 4));
    castw<<<dim3(WE / 1024, 1, 4), 256, 0, stream>>>(wq, wk, wv, wo,
                                                     wqh, wkh, wvh, woh);

    gemm_qkv<<<dim3((B_ * T_) / 128, D_ / 128, 3), 256, 0, stream>>>(
        xh, wqh, wkh, wvh, qh, kh, vth);

    flash_mfma<<<dim3(B_ * H_, 16, 1), 256, 0, stream>>>(qh, kh, vth, oh);

    gemm_wo<<<dim3((B_ * T_) / 128, D_ / 128, 1), 256, 0, stream>>>(oh, woh, out);
}